// Round 1
// baseline (646.003 us; speedup 1.0000x reference)
//
#include <hip/hip_runtime.h>

// Problem constants (from reference):
//   B=256, C=8, M=16, N=4096, R=D=64, CM=C*M=128
//   outputs[b,n] = sum_cm x[b,cm,n] * w[cm]          (512 MiB in, 4 MiB out)
//   idx = argmax_n outputs[b,:]  (first-max tiebreak)
//   r = trunc(r_target[idx/64]); d = trunc(d_target[idx%64])
//   flat out = [outputs (B*N), d (B), r (B), d (B)]
//
// Single kernel: one 1024-thread block per batch row (256 blocks = 1/CU).
// R1 change: a 1024-thread block forces 4 waves/SIMD co-residency, i.e. a
// HARD 128-VGPR cap. The old loop staged v4f v[16] (64 VGPRs) with
// #pragma unroll 2 (~160-190 VGPRs wanted) -> scratch spills -> ~3x HBM
// traffic. New loop: groups of 8 rows (32 VGPRs staging), FULLY unrolled
// (all 16 groups, every index compile-time) so the scheduler overlaps
// adjacent groups' loads with FMAs up to the 128-VGPR cap, spill-free.
// 8 loads/wave in flight x 16 waves/CU = 128 KiB/CU >> BW-delay share.

#define BATCH   256
#define NDIM    4096
#define CM      128
#define THREADS 1024
#define NWAVES  (THREADS / 64)
#define GROUP   8
#define NGROUPS (CM / GROUP)   // 16

typedef float v4f __attribute__((ext_vector_type(4)));  // clang-native for nontemporal builtin

__global__ __launch_bounds__(THREADS, 4) void conv_argmax_kernel(
    const float* __restrict__ x, const float* __restrict__ W,
    const float* __restrict__ r_target, const float* __restrict__ d_target,
    float* __restrict__ out)
{
    __shared__ float w[CM];
    __shared__ float sval[NWAVES];
    __shared__ int   sidx[NWAVES];

    const int b   = blockIdx.x;
    const int tid = threadIdx.x;

    if (tid < CM) w[tid] = W[tid];
    __syncthreads();

    const int n0 = tid * 4;                       // this thread's 4 columns
    const float* xp = x + (size_t)b * (CM * NDIM) + n0;

    float acc0 = 0.f, acc1 = 0.f, acc2 = 0.f, acc3 = 0.f;

    // Fully unrolled: 16 groups x (8 nontemporal dwordx4 loads + 8 FMA rows).
    // One straight-line basic block -> list scheduler hoists next group's
    // loads over current group's FMAs, bounded by the 128-VGPR cap.
    #pragma unroll
    for (int g = 0; g < NGROUPS; ++g) {
        v4f v[GROUP];
        #pragma unroll
        for (int j = 0; j < GROUP; ++j) {
            v[j] = __builtin_nontemporal_load(
                (const v4f*)(xp + (size_t)(g * GROUP + j) * NDIM));
        }
        #pragma unroll
        for (int j = 0; j < GROUP; ++j) {
            const float wc = w[g * GROUP + j];   // uniform ds_read broadcast
            acc0 += v[j].x * wc;
            acc1 += v[j].y * wc;
            acc2 += v[j].z * wc;
            acc3 += v[j].w * wc;
        }
    }

    // Streaming store of this thread's 4 outputs (no reuse -> nontemporal).
    v4f o;
    o.x = acc0; o.y = acc1; o.z = acc2; o.w = acc3;
    __builtin_nontemporal_store(o, (v4f*)(out + (size_t)b * NDIM + n0));

    // Thread-local argmax (ascending index => first-occurrence tiebreak,
    // matching jnp.argmax).
    float bv = acc0; int bi = n0;
    if (acc1 > bv) { bv = acc1; bi = n0 + 1; }
    if (acc2 > bv) { bv = acc2; bi = n0 + 2; }
    if (acc3 > bv) { bv = acc3; bi = n0 + 3; }

    // Wave (64-lane) reduction: larger value wins; equal value -> smaller index.
    for (int off = 32; off >= 1; off >>= 1) {
        float ov = __shfl_down(bv, off, 64);
        int   oi = __shfl_down(bi, off, 64);
        if (ov > bv || (ov == bv && oi < bi)) { bv = ov; bi = oi; }
    }
    const int wave = tid >> 6;
    if ((tid & 63) == 0) { sval[wave] = bv; sidx[wave] = bi; }
    __syncthreads();

    if (tid == 0) {
        #pragma unroll
        for (int i = 1; i < NWAVES; ++i) {
            if (sval[i] > bv || (sval[i] == bv && sidx[i] < bi)) {
                bv = sval[i]; bi = sidx[i];
            }
        }
        const int r_index = bi >> 6;      // idx // 64  (len_r == 64)
        const int d_index = bi & 63;      // idx % 64   (len_d == 64)
        // Reference assigns float into int tensor: truncation toward zero.
        const float r = (float)(int)r_target[r_index];
        const float d = (float)(int)d_target[d_index];
        const int BN = BATCH * NDIM;
        out[BN + b]             = d;      // second return element: d
        out[BN + BATCH + b]     = r;      // output tuple: r
        out[BN + 2 * BATCH + b] = d;      // output tuple: d
    }
}

extern "C" void kernel_launch(void* const* d_in, const int* in_sizes, int n_in,
                              void* d_out, int out_size, void* d_ws, size_t ws_size,
                              hipStream_t stream) {
    const float* x        = (const float*)d_in[0];  // [B, C, M, N] = [256,8,16,4096]
    const float* W        = (const float*)d_in[1];  // [1, C, M, 1] -> 128 floats, idx c*16+m
    const float* r_target = (const float*)d_in[2];  // [64]
    const float* d_target = (const float*)d_in[3];  // [64]
    float* out = (float*)d_out;

    conv_argmax_kernel<<<BATCH, THREADS, 0, stream>>>(x, W, r_target, d_target, out);
}